// Round 10
// baseline (308.774 us; speedup 1.0000x reference)
//
#include <hip/hip_runtime.h>
#include <hip/hip_cooperative_groups.h>
#include <hip/hip_bf16.h>

namespace cg = cooperative_groups;

#define LSEQ 2048
#define BB 2
#define DD 128
#define HH 8
#define HD 32

#define FPSCALE 524288.0f            // 2^19 fixed-point scale for S
#define RFPSCALE (1.0f / 524288.0f)
#define DENSCALE 65536.0f            // 2^16 fixed-point scale for den
#define QSCALE 0.25503486f           // (1/sqrt(32)) * log2(e)  -> use exp2
#define SSTRIDE 332

typedef __bf16 bf8_t __attribute__((ext_vector_type(8)));
typedef __bf16 bf4_t __attribute__((ext_vector_type(4)));
typedef float f4_t __attribute__((ext_vector_type(4)));

__global__ __launch_bounds__(256, 2) void k_mega(
        const float* __restrict__ x,  const float* __restrict__ pe,
        const float* __restrict__ Wq, const float* __restrict__ Wk,
        const float* __restrict__ Wv, const float* __restrict__ bq,
        const float* __restrict__ bk,
        float* __restrict__ w, __bf16* __restrict__ Qb, __bf16* __restrict__ Kb,
        int* __restrict__ Si, int* __restrict__ denI, float* __restrict__ out) {
    cg::grid_group grid = cg::this_grid();
    __shared__ __align__(16) char smem[34816];
    int gb = blockIdx.x;
    int tid = threadIdx.x;
    int wid = tid >> 6, lane = tid & 63;
    int lm = lane & 15, lq = lane >> 4;

    // ================ phase 1: QK GEMM (all) + wv + zero ================
    {
        __bf16* xs = (__bf16*)smem;                   // 64 x 136
        __bf16* Wt = (__bf16*)(smem + 64 * 136 * 2);  // 64 x 136 (transposed)
        int jr = gb >> 3, y = gb & 7;
        int row0 = jr * 64;
        bool isK = y >= 4;
        int cbase = (y & 3) * 64;
        const float* W = isK ? Wk : Wq;

        #pragma unroll
        for (int i = 0; i < 8; i++) {
            int idx4 = tid + i * 256;                 // 0..2047 float4s
            int row = idx4 >> 5, col4 = idx4 & 31;
            float4 xv = ((const float4*)x)[row0 * 32 + idx4];
            float4 pv = ((const float4*)pe)[((row0 + row) & (LSEQ - 1)) * 32 + col4];
            bf4_t o = {(__bf16)(xv.x + pv.x), (__bf16)(xv.y + pv.y),
                       (__bf16)(xv.z + pv.z), (__bf16)(xv.w + pv.w)};
            *(bf4_t*)&xs[row * 136 + col4 * 4] = o;
        }
        #pragma unroll
        for (int i = 0; i < 8; i++) {
            int idx4 = tid + i * 256;                 // 0..2047
            int d = idx4 >> 4, c4 = (idx4 & 15) * 4;
            float4 wv4 = *(const float4*)(W + d * 256 + cbase + c4);
            Wt[(c4 + 0) * 136 + d] = (__bf16)wv4.x;
            Wt[(c4 + 1) * 136 + d] = (__bf16)wv4.y;
            Wt[(c4 + 2) * 136 + d] = (__bf16)wv4.z;
            Wt[(c4 + 3) * 136 + d] = (__bf16)wv4.w;
        }
        __syncthreads();

        int c0loc = wid * 16;
        f4_t acc0 = {0,0,0,0}, acc1 = {0,0,0,0}, acc2 = {0,0,0,0}, acc3 = {0,0,0,0};
        #pragma unroll
        for (int s = 0; s < 4; s++) {
            bf8_t bw = *(const bf8_t*)&Wt[(c0loc + lm) * 136 + lq * 8 + s * 32];
            bf8_t a0 = *(const bf8_t*)&xs[(0  + lm) * 136 + lq * 8 + s * 32];
            bf8_t a1 = *(const bf8_t*)&xs[(16 + lm) * 136 + lq * 8 + s * 32];
            bf8_t a2 = *(const bf8_t*)&xs[(32 + lm) * 136 + lq * 8 + s * 32];
            bf8_t a3 = *(const bf8_t*)&xs[(48 + lm) * 136 + lq * 8 + s * 32];
            acc0 = __builtin_amdgcn_mfma_f32_16x16x32_bf16(a0, bw, acc0, 0, 0, 0);
            acc1 = __builtin_amdgcn_mfma_f32_16x16x32_bf16(a1, bw, acc1, 0, 0, 0);
            acc2 = __builtin_amdgcn_mfma_f32_16x16x32_bf16(a2, bw, acc2, 0, 0, 0);
            acc3 = __builtin_amdgcn_mfma_f32_16x16x32_bf16(a3, bw, acc3, 0, 0, 0);
        }
        int c = cbase + c0loc + lm;
        float bv = (isK ? bk : bq)[c];
        float qs = isK ? 1.f : QSCALE;
        __bf16* Out = isK ? Kb : Qb;
        int h = c >> 5, hd = c & 31;
        f4_t accs[4] = {acc0, acc1, acc2, acc3};
        #pragma unroll
        for (int rs = 0; rs < 4; rs++) {
            #pragma unroll
            for (int r = 0; r < 4; r++) {
                int row = row0 + rs * 16 + lq * 4 + r;
                int b_ = row >> 11, l = row & (LSEQ - 1);
                Out[((h * BB + b_) * LSEQ + l) * HD + hd] =
                    (__bf16)((accs[rs][r] + bv) * qs);
            }
        }
    }
    // secondary roles
    if (gb < 128) {
        __syncthreads();                              // LDS reuse
        float* xsf = (float*)smem;                    // 32*132
        float* wvf = (float*)(smem + 32 * 132 * 4);   // 1024
        int r0 = gb * 32;
        for (int i = 0; i < 16; i++) {
            int idx = tid + i * 256;
            xsf[(idx >> 7) * 132 + (idx & 127)] = x[r0 * 128 + idx];
        }
        for (int i = 0; i < 4; i++) {
            int idx = tid + i * 256;
            wvf[idx] = Wv[idx];
        }
        __syncthreads();
        int rl = tid >> 3, h = tid & 7;
        float acc = 0.f;
        #pragma unroll 8
        for (int d = 0; d < 128; d++) acc += xsf[rl * 132 + d] * wvf[d * 8 + h];
        float sg = 1.f / (1.f + __expf(-acc));
        int r = r0 + rl;
        int b = r >> 11, l = r & (LSEQ - 1);
        w[(h * BB + b) * LSEQ + (LSEQ - 1 - l)] = sg;
    } else if (gb < 160) {
        int4 z = {0, 0, 0, 0};
        ((int4*)Si)[(gb - 128) * 256 + tid] = z;
    } else if (gb < 192) {
        int4 z = {0, 0, 0, 0};
        ((int4*)denI)[(gb - 160) * 256 + tid] = z;
    }
    grid.sync();

    // ================ phase 2: denominators (1024 units, 2/block) ================
    #pragma unroll
    for (int j = 0; j < 2; j++) {
        int u = gb + j * 512;
        int hb = u >> 6;
        int rem = u & 63;
        int q0 = (rem >> 2) * 128;
        int kbase = (rem & 3) * 512;
        int qa = q0 + wid * 16;
        int qb2 = qa + 64;

        bf8_t aqa = *(const bf8_t*)(Qb + (hb * LSEQ + qa + lm) * HD + lq * 8);
        bf8_t aqb = *(const bf8_t*)(Qb + (hb * LSEQ + qb2 + lm) * HD + lq * 8);
        const __bf16* Khb = Kb + hb * LSEQ * HD;

        float dsa[4] = {0.f, 0.f, 0.f, 0.f};
        float dsb[4] = {0.f, 0.f, 0.f, 0.f};
        #pragma unroll 4
        for (int s = 0; s < 32; s++) {
            bf8_t bk_ = *(const bf8_t*)(Khb + (kbase + s * 16 + lm) * HD + lq * 8);
            f4_t z = {0.f, 0.f, 0.f, 0.f};
            f4_t sa = __builtin_amdgcn_mfma_f32_16x16x32_bf16(aqa, bk_, z, 0, 0, 0);
            f4_t sb = __builtin_amdgcn_mfma_f32_16x16x32_bf16(aqb, bk_, z, 0, 0, 0);
            #pragma unroll
            for (int r = 0; r < 4; r++) { dsa[r] += exp2f(sa[r]); dsb[r] += exp2f(sb[r]); }
        }
        #pragma unroll
        for (int r = 0; r < 4; r++) {
            float va = dsa[r], vb = dsb[r];
            va += __shfl_xor(va, 1); vb += __shfl_xor(vb, 1);
            va += __shfl_xor(va, 2); vb += __shfl_xor(vb, 2);
            va += __shfl_xor(va, 4); vb += __shfl_xor(vb, 4);
            va += __shfl_xor(va, 8); vb += __shfl_xor(vb, 8);
            dsa[r] = va; dsb[r] = vb;
        }
        if (lm == 0) {
            #pragma unroll
            for (int r = 0; r < 4; r++) {
                atomicAdd(&denI[hb * LSEQ + qa + lq * 4 + r],
                          __float2int_rn(dsa[r] * DENSCALE));
                atomicAdd(&denI[hb * LSEQ + qb2 + lq * 4 + r],
                          __float2int_rn(dsb[r] * DENSCALE));
            }
        }
    }
    grid.sync();

    // ================ phase 3: triangle scatter (2304 live tiles) ================
    {
        int* Sloc = (int*)smem;                       // 16*SSTRIDE ints = 21248 B
        float* lwt = (float*)(smem + 16 * SSTRIDE * 4); // 1024 B
        for (int t = gb; t < 2304; t += 512) {
            int hb = t / 144;
            int s = t - hb * 144;
            int kc = 0;                               // kc: cumulative 2k(k+1) <= s
            while (2 * (kc + 1) * (kc + 2) <= s) kc++;
            int q0i = s - 2 * kc * (kc + 1);          // 0 .. 4(kc+1)-1
            int q0 = q0i * 64;
            int kc0 = kc * 256;

            for (int i = tid; i < 16 * SSTRIDE; i += 256) Sloc[i] = 0;
            lwt[tid] = log2f(w[hb * LSEQ + kc0 + tid]);

            int qw0 = q0 + wid * 16;
            bf8_t aq = *(const bf8_t*)(Qb + (hb * LSEQ + qw0 + lm) * HD + lq * 8);
            float lrd[4];
            #pragma unroll
            for (int r = 0; r < 4; r++)
                lrd[r] = log2f(DENSCALE * FPSCALE /
                               (float)denI[hb * LSEQ + qw0 + lq * 4 + r]);
            __syncthreads();

            const __bf16* Khb = Kb + hb * LSEQ * HD;
            int mbase = kc0 - q0 - 63;
            int qrow = qw0 + lq * 4;
            int* mySloc = Sloc + (wid * 4 + lq) * SSTRIDE;
            int sub_start = (qw0 > kc0) ? ((qw0 - kc0) >> 4) : 0;

            {   // boundary subtile
                int k0s = kc0 + sub_start * 16;
                bf8_t bk_ = *(const bf8_t*)(Khb + (k0s + lm) * HD + lq * 8);
                f4_t z = {0.f, 0.f, 0.f, 0.f};
                f4_t sc = __builtin_amdgcn_mfma_f32_16x16x32_bf16(aq, bk_, z, 0, 0, 0);
                float lw = lwt[sub_start * 16 + lm];
                int kcol = k0s + lm;
                #pragma unroll
                for (int r = 0; r < 4; r++) {
                    int m = kcol - (qrow + r);
                    if (m >= 0) {
                        int iv = __float2int_rn(exp2f(sc[r] + lrd[r] + lw));
                        atomicAdd(&mySloc[m - mbase], iv);
                    }
                }
            }
            #pragma unroll 4
            for (int sub = sub_start + 1; sub < 16; sub++) {
                int k0s = kc0 + sub * 16;
                bf8_t bk_ = *(const bf8_t*)(Khb + (k0s + lm) * HD + lq * 8);
                f4_t z = {0.f, 0.f, 0.f, 0.f};
                f4_t sc = __builtin_amdgcn_mfma_f32_16x16x32_bf16(aq, bk_, z, 0, 0, 0);
                float lw = lwt[sub * 16 + lm];
                int kcol = k0s + lm;
                #pragma unroll
                for (int r = 0; r < 4; r++) {
                    int m = kcol - (qrow + r);
                    int iv = __float2int_rn(exp2f(sc[r] + lrd[r] + lw));
                    atomicAdd(&mySloc[m - mbase], iv);
                }
            }
            __syncthreads();
            for (int i = tid; i < 320; i += 256) {
                int m = mbase + i;
                int v = 0;
                #pragma unroll
                for (int sl = 0; sl < 16; sl++) v += Sloc[sl * SSTRIDE + i];
                if (m >= 0 && m < LSEQ && v != 0)
                    atomicAdd(&Si[hb * LSEQ + m], v);
            }
            __syncthreads();                          // before next-iter rezero
        }
    }
    grid.sync();

    // ================ phase 4: pooling epilogue ================
    if (gb < 128) {
        int idx = gb * 256 + tid;                     // (b*2048 + m)*8 + h
        int h = idx & 7;
        int m = (idx >> 3) & (LSEQ - 1);
        int b = idx >> 14;
        const int* Sr = Si + (h * BB + b) * LSEQ;
        float s = (float)Sr[m];
        float cnt = 3.f;
        if (m > 0) s += (float)Sr[m - 1]; else cnt = 2.f;
        if (m < LSEQ - 1) s += (float)Sr[m + 1]; else cnt = 2.f;
        out[idx] = s * RFPSCALE / cnt;
    }
}

extern "C" void kernel_launch(void* const* d_in, const int* in_sizes, int n_in,
                              void* d_out, int out_size, void* d_ws, size_t ws_size,
                              hipStream_t stream) {
    const float* x  = (const float*)d_in[0];
    const float* pe = (const float*)d_in[1];
    const float* Wq = (const float*)d_in[2];
    const float* bq = (const float*)d_in[3];
    const float* Wk = (const float*)d_in[4];
    const float* bk = (const float*)d_in[5];
    const float* Wv = (const float*)d_in[6];
    float* out = (float*)d_out;

    char* ws = (char*)d_ws;
    int*    Si   = (int*)(ws);                              // 128 KB
    float*  w    = (float*)(ws + 131072);                   // 128 KB
    __bf16* Qb   = (__bf16*)(ws + 262144);                  // 2 MB
    __bf16* Kb   = (__bf16*)(ws + 262144 + 2097152);        // 2 MB
    int*    denI = (int*)(ws + 262144 + 4194304);           // 128 KB

    void* args[] = {(void*)&x, (void*)&pe, (void*)&Wq, (void*)&Wk, (void*)&Wv,
                    (void*)&bq, (void*)&bk, (void*)&w, (void*)&Qb, (void*)&Kb,
                    (void*)&Si, (void*)&denI, (void*)&out};
    hipLaunchCooperativeKernel((void*)k_mega, dim3(512), dim3(256), args, 0, stream);
}

// Round 11
// 127.772 us; speedup vs baseline: 2.4166x; 2.4166x over previous
//
#include <hip/hip_runtime.h>
#include <hip/hip_bf16.h>

#define LSEQ 2048
#define BB 2
#define DD 128
#define HH 8
#define HD 32

#define FPSCALE 524288.0f            // 2^19 fixed-point scale for S
#define RFPSCALE (1.0f / 524288.0f)
#define DENSCALE 65536.0f            // 2^16 fixed-point scale for den
#define QSCALE 0.25503486f           // (1/sqrt(32)) * log2(e)  -> use exp2

typedef __bf16 bf8_t __attribute__((ext_vector_type(8)));
typedef __bf16 bf4_t __attribute__((ext_vector_type(4)));
typedef float f4_t __attribute__((ext_vector_type(4)));

// ---------------- kernel A: QK-GEMM + wv sigmoid + zero Si/denI ----------
// blocks 0..511   : Q/K = (x+pe) @ W (+bias); 64 rows x 64 cols per block
// blocks 512..639 : w[hb][k] = sigmoid(x[b,L-1-k] . Wv[:,h])
// blocks 640..671 : zero Si (int4)
// blocks 672..703 : zero denI (int4)
__global__ __launch_bounds__(256) void k_A(const float* __restrict__ x,
                                           const float* __restrict__ pe,
                                           const float* __restrict__ Wq,
                                           const float* __restrict__ Wk,
                                           const float* __restrict__ Wv,
                                           const float* __restrict__ bq,
                                           const float* __restrict__ bk,
                                           float* __restrict__ w,
                                           __bf16* __restrict__ Qb,
                                           __bf16* __restrict__ Kb,
                                           int* __restrict__ Si,
                                           int* __restrict__ denI) {
    __shared__ __align__(16) char smem[34816];
    int gb = blockIdx.x;
    int tid = threadIdx.x;

    if (gb < 512) {
        // ---- QK GEMM role: 64 rows x 64 cols ----
        __bf16* xs = (__bf16*)smem;                   // 64 x 136
        __bf16* Wt = (__bf16*)(smem + 64 * 136 * 2);  // 64 x 136 (c-major, transposed)
        int jr = gb >> 3, y = gb & 7;
        int row0 = jr * 64;
        bool isK = y >= 4;
        int cbase = (y & 3) * 64;
        const float* W = isK ? Wk : Wq;

        // stage x+pe -> bf16 LDS (64 rows x 128 cols), float4 loads
        #pragma unroll
        for (int i = 0; i < 8; i++) {
            int idx4 = tid + i * 256;                 // 0..2047 float4s
            int row = idx4 >> 5, col4 = idx4 & 31;
            float4 xv = ((const float4*)x)[row0 * 32 + idx4];
            float4 pv = ((const float4*)pe)[((row0 + row) & (LSEQ - 1)) * 32 + col4];
            bf4_t o = {(__bf16)(xv.x + pv.x), (__bf16)(xv.y + pv.y),
                       (__bf16)(xv.z + pv.z), (__bf16)(xv.w + pv.w)};
            *(bf4_t*)&xs[row * 136 + col4 * 4] = o;
        }
        // stage W stripe transposed: Wt[c][d] = W[d][cbase+c]
        #pragma unroll
        for (int i = 0; i < 8; i++) {
            int idx4 = tid + i * 256;                 // 0..2047
            int d = idx4 >> 4, c4 = (idx4 & 15) * 4;
            float4 wv4 = *(const float4*)(W + d * 256 + cbase + c4);
            Wt[(c4 + 0) * 136 + d] = (__bf16)wv4.x;
            Wt[(c4 + 1) * 136 + d] = (__bf16)wv4.y;
            Wt[(c4 + 2) * 136 + d] = (__bf16)wv4.z;
            Wt[(c4 + 3) * 136 + d] = (__bf16)wv4.w;
        }
        __syncthreads();

        int wid = tid >> 6, lane = tid & 63;
        int lm = lane & 15, lq = lane >> 4;
        int c0loc = wid * 16;
        f4_t acc0 = {0,0,0,0}, acc1 = {0,0,0,0}, acc2 = {0,0,0,0}, acc3 = {0,0,0,0};
        #pragma unroll
        for (int s = 0; s < 4; s++) {
            bf8_t bw = *(const bf8_t*)&Wt[(c0loc + lm) * 136 + lq * 8 + s * 32];
            bf8_t a0 = *(const bf8_t*)&xs[(0  + lm) * 136 + lq * 8 + s * 32];
            bf8_t a1 = *(const bf8_t*)&xs[(16 + lm) * 136 + lq * 8 + s * 32];
            bf8_t a2 = *(const bf8_t*)&xs[(32 + lm) * 136 + lq * 8 + s * 32];
            bf8_t a3 = *(const bf8_t*)&xs[(48 + lm) * 136 + lq * 8 + s * 32];
            acc0 = __builtin_amdgcn_mfma_f32_16x16x32_bf16(a0, bw, acc0, 0, 0, 0);
            acc1 = __builtin_amdgcn_mfma_f32_16x16x32_bf16(a1, bw, acc1, 0, 0, 0);
            acc2 = __builtin_amdgcn_mfma_f32_16x16x32_bf16(a2, bw, acc2, 0, 0, 0);
            acc3 = __builtin_amdgcn_mfma_f32_16x16x32_bf16(a3, bw, acc3, 0, 0, 0);
        }
        int c = cbase + c0loc + lm;                   // 0..255
        float bv = (isK ? bk : bq)[c];
        float qs = isK ? 1.f : QSCALE;
        __bf16* Out = isK ? Kb : Qb;
        int h = c >> 5, hd = c & 31;
        f4_t accs[4] = {acc0, acc1, acc2, acc3};
        #pragma unroll
        for (int rs = 0; rs < 4; rs++) {
            #pragma unroll
            for (int r = 0; r < 4; r++) {
                int row = row0 + rs * 16 + lq * 4 + r;   // = b*2048 + l
                int b_ = row >> 11, l = row & (LSEQ - 1);
                Out[((h * BB + b_) * LSEQ + l) * HD + hd] =
                    (__bf16)((accs[rs][r] + bv) * qs);
            }
        }
    } else if (gb < 640) {
        // ---- wv sigmoid role ----
        float* xsf = (float*)smem;                    // 32*132
        float* wvf = (float*)(smem + 32 * 132 * 4);   // 1024
        int r0 = (gb - 512) * 32;
        for (int i = 0; i < 16; i++) {
            int idx = tid + i * 256;
            xsf[(idx >> 7) * 132 + (idx & 127)] = x[r0 * 128 + idx];
        }
        for (int i = 0; i < 4; i++) {
            int idx = tid + i * 256;
            wvf[idx] = Wv[idx];
        }
        __syncthreads();
        int rl = tid >> 3, h = tid & 7;
        float acc = 0.f;
        #pragma unroll 8
        for (int d = 0; d < 128; d++) acc += xsf[rl * 132 + d] * wvf[d * 8 + h];
        float sg = 1.f / (1.f + __expf(-acc));
        int r = r0 + rl;
        int b = r >> 11, l = r & (LSEQ - 1);
        w[(h * BB + b) * LSEQ + (LSEQ - 1 - l)] = sg;
    } else if (gb < 672) {
        int4 z = {0, 0, 0, 0};
        ((int4*)Si)[(gb - 640) * 256 + tid] = z;
    } else {
        int4 z = {0, 0, 0, 0};
        ((int4*)denI)[(gb - 672) * 256 + tid] = z;
    }
}

// ---------------- kernel 2a: fixed-point softmax denominators --------------
__global__ __launch_bounds__(256) void k_den(const __bf16* __restrict__ Qb,
                                             const __bf16* __restrict__ Kb,
                                             int* __restrict__ denI) {
    int hb = blockIdx.z;
    int q0 = blockIdx.y * 64;
    int kbase = blockIdx.x * 512;                   // k-quarter
    int wid = threadIdx.x >> 6, lane = threadIdx.x & 63;
    int lm = lane & 15, lq = lane >> 4;
    int qw0 = q0 + wid * 16;

    bf8_t aq = *(const bf8_t*)(Qb + (hb * LSEQ + qw0 + lm) * HD + lq * 8);
    const __bf16* Khb = Kb + hb * LSEQ * HD;

    float dsum[4] = {0.f, 0.f, 0.f, 0.f};
    #pragma unroll 4
    for (int s = 0; s < 32; s++) {
        bf8_t bk_ = *(const bf8_t*)(Khb + (kbase + s * 16 + lm) * HD + lq * 8);
        f4_t z = {0.f, 0.f, 0.f, 0.f};
        f4_t sc = __builtin_amdgcn_mfma_f32_16x16x32_bf16(aq, bk_, z, 0, 0, 0);
        #pragma unroll
        for (int r = 0; r < 4; r++) dsum[r] += exp2f(sc[r]);
    }
    #pragma unroll
    for (int r = 0; r < 4; r++) {
        float v = dsum[r];
        v += __shfl_xor(v, 1);
        v += __shfl_xor(v, 2);
        v += __shfl_xor(v, 4);
        v += __shfl_xor(v, 8);
        dsum[r] = v;
    }
    if (lm == 0) {
        #pragma unroll
        for (int r = 0; r < 4; r++)
            atomicAdd(&denI[hb * LSEQ + qw0 + lq * 4 + r],
                      __float2int_rn(dsum[r] * DENSCALE));
    }
}

// ---------------- kernel 2b: triangle scatter, divergence-free body --------
__global__ __launch_bounds__(256) void k_scat(const __bf16* __restrict__ Qb,
                                              const __bf16* __restrict__ Kb,
                                              const float* __restrict__ w,
                                              const int* __restrict__ denI,
                                              int* __restrict__ S) {
    int hb = blockIdx.z;
    int q0 = blockIdx.y * 64;
    int kc0 = blockIdx.x * 256;
    if (kc0 + 256 <= q0) return;                    // entirely below diagonal

    __shared__ int Sloc[4 * 320];
    __shared__ float wt[256];
    int tid = threadIdx.x;
    for (int i = tid; i < 1280; i += 256) Sloc[i] = 0;
    wt[tid] = w[hb * LSEQ + kc0 + tid] * FPSCALE;   // fold fixed-point scale in

    int wid = tid >> 6, lane = tid & 63;
    int lm = lane & 15, lq = lane >> 4;
    int qw0 = q0 + wid * 16;
    bf8_t aq = *(const bf8_t*)(Qb + (hb * LSEQ + qw0 + lm) * HD + lq * 8);
    float rdv[4];
    #pragma unroll
    for (int r = 0; r < 4; r++)
        rdv[r] = DENSCALE / (float)denI[hb * LSEQ + qw0 + lq * 4 + r];
    __syncthreads();

    const __bf16* Khb = Kb + hb * LSEQ * HD;
    int mbase = kc0 - q0 - 63;
    int qrow = qw0 + lq * 4;
    int* mySloc = Sloc + wid * 320;

    // per-wave first subtile that intersects the triangle
    int sub_start = (qw0 > kc0) ? ((qw0 - kc0) >> 4) : 0;

    // boundary subtile: per-element m>=0 check
    {
        int k0s = kc0 + sub_start * 16;
        bf8_t bk_ = *(const bf8_t*)(Khb + (k0s + lm) * HD + lq * 8);
        f4_t z = {0.f, 0.f, 0.f, 0.f};
        f4_t sc = __builtin_amdgcn_mfma_f32_16x16x32_bf16(aq, bk_, z, 0, 0, 0);
        float wvs = wt[sub_start * 16 + lm];
        int kcol = k0s + lm;
        #pragma unroll
        for (int r = 0; r < 4; r++) {
            int m = kcol - (qrow + r);
            if (m >= 0) {
                int iv = __float2int_rn(exp2f(sc[r]) * rdv[r] * wvs);
                atomicAdd(&mySloc[m - mbase], iv);
            }
        }
    }
    // main loop: strictly above diagonal, check-free
    #pragma unroll 4
    for (int sub = sub_start + 1; sub < 16; sub++) {
        int k0s = kc0 + sub * 16;
        bf8_t bk_ = *(const bf8_t*)(Khb + (k0s + lm) * HD + lq * 8);
        f4_t z = {0.f, 0.f, 0.f, 0.f};
        f4_t sc = __builtin_amdgcn_mfma_f32_16x16x32_bf16(aq, bk_, z, 0, 0, 0);
        float wvs = wt[sub * 16 + lm];
        int kcol = k0s + lm;
        #pragma unroll
        for (int r = 0; r < 4; r++) {
            int m = kcol - (qrow + r);
            int iv = __float2int_rn(exp2f(sc[r]) * rdv[r] * wvs);
            atomicAdd(&mySloc[m - mbase], iv);      // native ds_add, wave-private
        }
    }
    __syncthreads();
    for (int i = tid; i < 320; i += 256) {
        int m = mbase + i;
        int v = Sloc[i] + Sloc[320 + i] + Sloc[640 + i] + Sloc[960 + i];
        if (m >= 0 && m < LSEQ && v != 0)
            atomicAdd(&S[hb * LSEQ + m], v);        // native int global atomic
    }
}

// ---------------- kernel 3: pooling epilogue (int -> float) ----------------
__global__ __launch_bounds__(256) void k_out(const int* __restrict__ S,
                                             float* __restrict__ out) {
    int idx = blockIdx.x * 256 + threadIdx.x;       // (b*2048 + m)*8 + h
    int h = idx & 7;
    int m = (idx >> 3) & (LSEQ - 1);
    int b = idx >> 14;
    const int* Sr = S + (h * BB + b) * LSEQ;
    float s = (float)Sr[m];
    float cnt = 3.f;
    if (m > 0) s += (float)Sr[m - 1]; else cnt = 2.f;
    if (m < LSEQ - 1) s += (float)Sr[m + 1]; else cnt = 2.f;
    out[idx] = s * RFPSCALE / cnt;
}

extern "C" void kernel_launch(void* const* d_in, const int* in_sizes, int n_in,
                              void* d_out, int out_size, void* d_ws, size_t ws_size,
                              hipStream_t stream) {
    const float* x  = (const float*)d_in[0];
    const float* pe = (const float*)d_in[1];
    const float* Wq = (const float*)d_in[2];
    const float* bq = (const float*)d_in[3];
    const float* Wk = (const float*)d_in[4];
    const float* bk = (const float*)d_in[5];
    const float* Wv = (const float*)d_in[6];
    float* out = (float*)d_out;

    char* ws = (char*)d_ws;
    int*    Si   = (int*)(ws);                              // 128 KB
    float*  w    = (float*)(ws + 131072);                   // 128 KB
    __bf16* Qb   = (__bf16*)(ws + 262144);                  // 2 MB
    __bf16* Kb   = (__bf16*)(ws + 262144 + 2097152);        // 2 MB
    int*    denI = (int*)(ws + 262144 + 4194304);           // 128 KB

    k_A<<<704, 256, 0, stream>>>(x, pe, Wq, Wk, Wv, bq, bk, w, Qb, Kb, Si, denI);
    k_den<<<dim3(4, 32, 16), 256, 0, stream>>>(Qb, Kb, denI);
    k_scat<<<dim3(8, 32, 16), 256, 0, stream>>>(Qb, Kb, w, denI, Si);
    k_out<<<128, 256, 0, stream>>>(Si, out);
}